// Round 4
// baseline (257.781 us; speedup 1.0000x reference)
//
#include <hip/hip_runtime.h>
#include <hip/hip_fp16.h>

#define N_NODES 100000
#define N_EDGES 1250000
#define C 64
#define NPB 128          // nodes per bucket (dst >> 7)
#define NB 782           // ceil(100000/128)
#define CAP 2048         // bucket capacity (mean 1598, sigma ~40 -> 11 sigma headroom)
#define P1_CHUNKQ 512    // int4-quads per partition block = 2048 edges
#define P1_BLOCKS 611    // ceil(312500 / 512)
#define NQ (N_EDGES / 4) // 312500

typedef int vint4 __attribute__((ext_vector_type(4)));
typedef _Float16 f16x8 __attribute__((ext_vector_type(8)));
typedef float f32x4 __attribute__((ext_vector_type(4)));

// ---------------- pass 1: partition edges into 128-node dst-buckets ----------------
__global__ __launch_bounds__(256) void partition_kernel(
        const int* __restrict__ src, const int* __restrict__ dst,
        int* __restrict__ gcnt, unsigned int* __restrict__ packed) {
    __shared__ int s_hist[4][NB];  // 12.5 KB
    __shared__ int s_cur[NB];      // 3.1 KB
    const int t = threadIdx.x;
    const int w = t >> 6;
    for (int i = t; i < 4 * NB; i += 256) ((int*)s_hist)[i] = 0;
    __syncthreads();

    const int qbase = blockIdx.x * P1_CHUNKQ;
    const vint4* d4 = (const vint4*)dst;
    const vint4* s4 = (const vint4*)src;

    vint4 dreg[2], sreg[2];
    bool val[2];
#pragma unroll
    for (int k = 0; k < 2; ++k) {
        int q = qbase + k * 256 + t;
        val[k] = q < NQ;
        if (val[k]) {
            dreg[k] = __builtin_nontemporal_load(&d4[q]);
            sreg[k] = __builtin_nontemporal_load(&s4[q]);
        }
    }

#pragma unroll
    for (int k = 0; k < 2; ++k) {
        if (val[k]) {
            atomicAdd(&s_hist[w][dreg[k].x >> 7], 1);
            atomicAdd(&s_hist[w][dreg[k].y >> 7], 1);
            atomicAdd(&s_hist[w][dreg[k].z >> 7], 1);
            atomicAdd(&s_hist[w][dreg[k].w >> 7], 1);
        }
    }
    __syncthreads();

    for (int b = t; b < NB; b += 256) {
        int tot = s_hist[0][b] + s_hist[1][b] + s_hist[2][b] + s_hist[3][b];
        s_cur[b] = (tot > 0) ? (b * CAP + atomicAdd(&gcnt[b], tot)) : 0;
    }
    __syncthreads();

#pragma unroll
    for (int k = 0; k < 2; ++k) {
        if (val[k]) {
            int bb, pos;
            bb = dreg[k].x >> 7; pos = atomicAdd(&s_cur[bb], 1);
            if (pos < (bb + 1) * CAP) packed[pos] = ((unsigned)sreg[k].x << 7) | (unsigned)(dreg[k].x & 127);
            bb = dreg[k].y >> 7; pos = atomicAdd(&s_cur[bb], 1);
            if (pos < (bb + 1) * CAP) packed[pos] = ((unsigned)sreg[k].y << 7) | (unsigned)(dreg[k].y & 127);
            bb = dreg[k].z >> 7; pos = atomicAdd(&s_cur[bb], 1);
            if (pos < (bb + 1) * CAP) packed[pos] = ((unsigned)sreg[k].z << 7) | (unsigned)(dreg[k].z & 127);
            bb = dreg[k].w >> 7; pos = atomicAdd(&s_cur[bb], 1);
            if (pos < (bb + 1) * CAP) packed[pos] = ((unsigned)sreg[k].w << 7) | (unsigned)(dreg[k].w & 127);
        }
    }
}

// ---------------- pass 2: per-bucket counting sort -> CSR (prefix inline) ----------------
__global__ __launch_bounds__(256) void sort_kernel(
        const unsigned int* __restrict__ packed,
        const int* __restrict__ gcnt,
        int* __restrict__ offsets, int* __restrict__ sorted_src) {
    __shared__ int s_part[256];
    __shared__ unsigned int s_e[CAP];  // 8 KB
    __shared__ int s_hist[NPB];
    __shared__ int s_excl[NPB];
    const int b = blockIdx.x;
    const int t = threadIdx.x;

    // inline exclusive prefix over L2-hot gcnt[0..b-1]
    int psum = 0;
    for (int i = t; i < b; i += 256) psum += gcnt[i];
    s_part[t] = psum;
    __syncthreads();
    for (int off = 128; off > 0; off >>= 1) {
        if (t < off) s_part[t] += s_part[t + off];
        __syncthreads();
    }
    const int base = s_part[0];
    const int nb = min(gcnt[b], CAP);

    for (int i = t; i < NPB; i += 256) s_hist[i] = 0;
    __syncthreads();
    // 4-wide NT reads of the bucket's packed run
    const vint4* p4 = (const vint4*)(packed + (size_t)b * CAP);
    for (int i4 = t; i4 * 4 < nb; i4 += 256) {
        vint4 u4 = __builtin_nontemporal_load(&p4[i4]);
        int i = i4 * 4;
        unsigned int u;
        u = (unsigned)u4.x; if (i + 0 < nb) { s_e[i + 0] = u; atomicAdd(&s_hist[u & 127u], 1); }
        u = (unsigned)u4.y; if (i + 1 < nb) { s_e[i + 1] = u; atomicAdd(&s_hist[u & 127u], 1); }
        u = (unsigned)u4.z; if (i + 2 < nb) { s_e[i + 2] = u; atomicAdd(&s_hist[u & 127u], 1); }
        u = (unsigned)u4.w; if (i + 3 < nb) { s_e[i + 3] = u; atomicAdd(&s_hist[u & 127u], 1); }
    }
    __syncthreads();
    if (t < NPB) s_excl[t] = s_hist[t];
    __syncthreads();
    for (int off = 1; off < NPB; off <<= 1) {
        int v = (t < NPB && t >= off) ? s_excl[t - off] : 0;
        __syncthreads();
        if (t < NPB) s_excl[t] += v;
        __syncthreads();
    }
    if (t < NPB) {
        int excl = s_excl[t] - s_hist[t];
        s_hist[t] = excl;  // becomes cursor
        int node = b * NPB + t;
        if (node < N_NODES) offsets[node] = base + excl;
    }
    __syncthreads();
    for (int i = t; i < nb; i += 256) {
        unsigned int u = s_e[i];
        int lp = atomicAdd(&s_hist[u & 127u], 1);
        sorted_src[base + lp] = (int)(u >> 7);
    }
    if (b == NB - 1 && t == 0) offsets[N_NODES] = N_EDGES;
}

// ---------------- dense (MFMA): [Z|R] = x @ [W_l|W_r] (+bias on R) --------
// 64 nodes/block, 4 waves, output 64x128 fp16. One fused B-tile [64k x 128out].
// A/B frags: contiguous-8 k loads, symmetric formula -> k-permutation cancels.
// C/D: col = lane&15, row = 4*(lane>>4)+j (m89-verified, dtype-independent).
#define AK 72   // padded k stride in halves (144 B, 16B-aligned)
#define OP 136  // s_o row stride in halves (272 B, 16B-aligned)

template <typename XT>
__global__ __launch_bounds__(256) void dense_mfma_kernel(
        const XT* __restrict__ x,
        const float* __restrict__ wl, const float* __restrict__ wr,
        const float* __restrict__ bl,
        __half* __restrict__ z, __half* __restrict__ r, int n_nodes) {
    // union: s_a[64][AK] | s_b[128][AK] during compute; s_o[64][OP] during epilogue
    __shared__ __align__(16) _Float16 smem[64 * AK + 128 * AK];  // 27648 B
    _Float16* s_a = smem;
    _Float16* s_b = smem + 64 * AK;
    _Float16* s_o = smem;  // 64*OP = 8704 halves, fits

    const int t = threadIdx.x;
    const int base = blockIdx.x * 64;

    // stage W_l|W_r transposed to frag order: s_b[outcol][k]
    for (int i = t; i < 4096; i += 256) {
        int k = i >> 6, n = i & 63;
        float vl = wl[i], vr = wr[i];
        s_b[n * AK + k]        = (_Float16)vl;
        s_b[(64 + n) * AK + k] = (_Float16)vr;
    }
    // stage x -> s_a[node][k] fp16
    if constexpr (sizeof(XT) == 4) {
        for (int i = t; i < 1024; i += 256) {
            int n = i >> 4, kq = i & 15;
            float4 v = make_float4(0.f, 0.f, 0.f, 0.f);
            if (base + n < n_nodes) v = ((const float4*)x)[(size_t)(base + n) * 16 + kq];
            _Float16* p = &s_a[n * AK + kq * 4];
            p[0] = (_Float16)v.x; p[1] = (_Float16)v.y;
            p[2] = (_Float16)v.z; p[3] = (_Float16)v.w;
        }
    } else {
        for (int i = t; i < 1024; i += 256) {
            int n = i >> 4, kq = i & 15;
            uint2 v = make_uint2(0u, 0u);
            if (base + n < n_nodes) v = ((const uint2*)x)[(size_t)(base + n) * 16 + kq];  // 16 uint2/row
            *(uint2*)&s_a[n * AK + kq * 4] = v;
        }
    }
    __syncthreads();

    const int lane = t & 63;
    const int w = t >> 6;
    const int mrow = w * 16 + (lane & 15);
    const int kg = (lane >> 4) * 8;
    const int cb = lane & 15;

    f16x8 a0 = *(const f16x8*)&s_a[mrow * AK + kg];       // k in [0,32)
    f16x8 a1 = *(const f16x8*)&s_a[mrow * AK + 32 + kg];  // k in [32,64)
    f32x4 acc[8];
#pragma unroll
    for (int nt = 0; nt < 8; ++nt) {
        int col = nt * 16 + cb;
        f16x8 b0 = *(const f16x8*)&s_b[col * AK + kg];
        f16x8 b1 = *(const f16x8*)&s_b[col * AK + 32 + kg];
        f32x4 c = {0.f, 0.f, 0.f, 0.f};
        c = __builtin_amdgcn_mfma_f32_16x16x32_f16(a0, b0, c, 0, 0, 0);
        c = __builtin_amdgcn_mfma_f32_16x16x32_f16(a1, b1, c, 0, 0, 0);
        acc[nt] = c;
    }
    __syncthreads();  // all LDS frag reads done -> safe to overlay s_o

    // epilogue: acc -> s_o[node][col], bias folded into R columns (col>=64)
#pragma unroll
    for (int nt = 0; nt < 8; ++nt) {
        int col = nt * 16 + cb;
        float bias = (nt >= 4) ? bl[col - 64] : 0.0f;
#pragma unroll
        for (int j = 0; j < 4; ++j) {
            int row = w * 16 + (lane >> 4) * 4 + j;
            s_o[row * OP + col] = (_Float16)(acc[nt][j] + bias);
        }
    }
    __syncthreads();

    // coalesced write-out: thread t -> row t>>2, 32-half (64 B) chunk (t&3)
    {
        int row = t >> 2, q = t & 3;
        size_t gn = (size_t)base + row;
        if (gn < (size_t)n_nodes) {
            const uint4* sp = (const uint4*)&s_o[row * OP + q * 32];
            __half* dp = (q < 2) ? (z + gn * 64 + q * 32) : (r + gn * 64 + (q - 2) * 32);
#pragma unroll
            for (int j = 0; j < 4; ++j)
                ((uint4*)dp)[j] = sp[j];
        }
    }
}

// ---------------- gather: h = PReLU( mean_j z[nbr_j] + r ) ----------------
// R15: 4 nodes/wave, 16 lanes/node, 8 B/lane (uint2 = 4 fp16 channels).
// Each row-load instr covers 4 rows; 16 predicated slots -> up to 64 rows
// in flight per wave (2x R12) to attack the latency*concurrency bound
// (measured 3.5 TB/s == 16 waves/CU x 32 lines / ~700 cyc round trip).
// Predication (i < rem) issues NO memory op for dead slots (kills the ~22%
// duplicate tail fetches of the clamped scheme).
template <typename OT>
__global__ __launch_bounds__(256) void gather_kernel(
        const __half* __restrict__ z,
        const __half* __restrict__ r,
        const int* __restrict__ offsets,
        const int* __restrict__ sorted_src,
        const float* __restrict__ a,
        OT* __restrict__ out) {
    const int lane = threadIdx.x & 63;
    const int c4 = lane & 15;                 // channel quad: [4*c4, 4*c4+4)
    const int sub = lane >> 4;                // node sub-index 0..3
    const int node = (blockIdx.x << 4) + ((threadIdx.x >> 6) << 2) + sub;

    const int beg = offsets[node];
    const int deg = offsets[node + 1] - beg;
    const int* sp = sorted_src + beg;
    const uint2* z4 = (const uint2*)z;        // 16 uint2 per 64-half row

    float4 acc = make_float4(0.f, 0.f, 0.f, 0.f);
    for (int j = 0; j < deg; j += 16) {
        const int rem = deg - j;
        int idx[16];
        uint2 v[16];
#pragma unroll
        for (int i = 0; i < 16; ++i)
            if (i < rem) idx[i] = sp[j + i];
#pragma unroll
        for (int i = 0; i < 16; ++i) {
            if (i < rem) v[i] = z4[(size_t)idx[i] * 16 + c4];
            else         v[i] = make_uint2(0u, 0u);
        }
#pragma unroll
        for (int i = 0; i < 16; ++i) {
            float2 f0 = __half22float2(*(const __half2*)&v[i].x);
            float2 f1 = __half22float2(*(const __half2*)&v[i].y);
            acc.x += f0.x; acc.y += f0.y; acc.z += f1.x; acc.w += f1.y;
        }
    }

    const float invd = 1.0f / (float)max(deg, 1);
    uint2 rv2 = ((const uint2*)r)[(size_t)node * 16 + c4];
    float2 r0 = __half22float2(*(const __half2*)&rv2.x);
    float2 r1 = __half22float2(*(const __half2*)&rv2.y);
    float4 av = ((const float4*)a)[c4];

    float h0 = acc.x * invd + r0.x;
    float h1 = acc.y * invd + r0.y;
    float h2 = acc.z * invd + r1.x;
    float h3 = acc.w * invd + r1.y;
    float o0 = h0 >= 0.0f ? h0 : av.x * h0;
    float o1 = h1 >= 0.0f ? h1 : av.y * h1;
    float o2 = h2 >= 0.0f ? h2 : av.z * h2;
    float o3 = h3 >= 0.0f ? h3 : av.w * h3;

    if constexpr (sizeof(OT) == 2) {
        __half2 p0 = __float22half2_rn(make_float2(o0, o1));
        __half2 p1 = __float22half2_rn(make_float2(o2, o3));
        uint2 pk;
        pk.x = *(const unsigned int*)&p0;
        pk.y = *(const unsigned int*)&p1;
        ((uint2*)out)[(size_t)node * 16 + c4] = pk;
    } else {
        ((float4*)out)[(size_t)node * 16 + c4] = make_float4(o0, o1, o2, o3);
    }
}

extern "C" void kernel_launch(void* const* d_in, const int* in_sizes, int n_in,
                              void* d_out, int out_size, void* d_ws, size_t ws_size,
                              hipStream_t stream) {
    const float* x    = (const float*)d_in[0];
    const int*   ei   = (const int*)d_in[1];
    const float* w_l0 = (const float*)d_in[2];
    const float* b_l0 = (const float*)d_in[3];
    const float* w_r0 = (const float*)d_in[4];
    const float* a0   = (const float*)d_in[5];
    const float* w_l1 = (const float*)d_in[6];
    const float* b_l1 = (const float*)d_in[7];
    const float* w_r1 = (const float*)d_in[8];
    const float* a1   = (const float*)d_in[9];
    float* out = (float*)d_out;

    const int* src = ei;            // edge_index[0, :]
    const int* dst = ei + N_EDGES;  // edge_index[1, :]

    // ws: gcnt[1024] | offsets[N+1] | packed[NB*CAP] | sorted_src[E] | Z | R | H (fp16 N*C each)
    int* gcnt            = (int*)d_ws;
    int* offsets         = gcnt + 1024;
    unsigned int* packed = (unsigned int*)(offsets + (N_NODES + 1));
    int* sorted_src      = (int*)(packed + (size_t)NB * CAP);
    __half* Z            = (__half*)(sorted_src + N_EDGES);
    __half* R            = Z + (size_t)N_NODES * C;
    __half* H            = R + (size_t)N_NODES * C;

    hipMemsetAsync(gcnt, 0, 1024 * sizeof(int), stream);

    const int dblocks = (N_NODES + 63) / 64;
    const int nblocks = N_NODES / 16;  // 4 nodes/wave * 4 waves = 16 nodes/block (6250)

    partition_kernel<<<P1_BLOCKS, 256, 0, stream>>>(src, dst, gcnt, packed);
    sort_kernel<<<NB, 256, 0, stream>>>(packed, gcnt, offsets, sorted_src);

    // Layer 0: dense fp32->fp16 (MFMA), gather -> H (fp16)
    dense_mfma_kernel<float><<<dblocks, 256, 0, stream>>>(x, w_l0, w_r0, b_l0, Z, R, N_NODES);
    gather_kernel<__half><<<nblocks, 256, 0, stream>>>(Z, R, offsets, sorted_src, a0, H);

    // Layer 1: dense fp16->fp16 (MFMA), gather -> d_out (fp32)
    dense_mfma_kernel<__half><<<dblocks, 256, 0, stream>>>(H, w_l1, w_r1, b_l1, Z, R, N_NODES);
    gather_kernel<float><<<nblocks, 256, 0, stream>>>(Z, R, offsets, sorted_src, a1, out);
}

// Round 5
// 241.173 us; speedup vs baseline: 1.0689x; 1.0689x over previous
//
#include <hip/hip_runtime.h>
#include <hip/hip_fp16.h>

#define N_NODES 100000
#define N_EDGES 1250000
#define C 64
#define NPB 128          // nodes per bucket (dst >> 7)
#define NB 782           // ceil(100000/128)
#define CAP 2048         // bucket capacity (mean 1598, sigma ~40 -> 11 sigma headroom)
#define P1_CHUNKQ 512    // int4-quads per partition block = 2048 edges
#define P1_BLOCKS 611    // ceil(312500 / 512)
#define NQ (N_EDGES / 4) // 312500

typedef int vint4 __attribute__((ext_vector_type(4)));
typedef _Float16 f16x8 __attribute__((ext_vector_type(8)));
typedef float f32x4 __attribute__((ext_vector_type(4)));

// ---------------- pass 1: partition edges into 128-node dst-buckets ----------------
__global__ __launch_bounds__(256) void partition_kernel(
        const int* __restrict__ src, const int* __restrict__ dst,
        int* __restrict__ gcnt, unsigned int* __restrict__ packed) {
    __shared__ int s_hist[4][NB];  // 12.5 KB
    __shared__ int s_cur[NB];      // 3.1 KB
    const int t = threadIdx.x;
    const int w = t >> 6;
    for (int i = t; i < 4 * NB; i += 256) ((int*)s_hist)[i] = 0;
    __syncthreads();

    const int qbase = blockIdx.x * P1_CHUNKQ;
    const vint4* d4 = (const vint4*)dst;
    const vint4* s4 = (const vint4*)src;

    vint4 dreg[2], sreg[2];
    bool val[2];
#pragma unroll
    for (int k = 0; k < 2; ++k) {
        int q = qbase + k * 256 + t;
        val[k] = q < NQ;
        if (val[k]) {
            dreg[k] = __builtin_nontemporal_load(&d4[q]);
            sreg[k] = __builtin_nontemporal_load(&s4[q]);
        }
    }

#pragma unroll
    for (int k = 0; k < 2; ++k) {
        if (val[k]) {
            atomicAdd(&s_hist[w][dreg[k].x >> 7], 1);
            atomicAdd(&s_hist[w][dreg[k].y >> 7], 1);
            atomicAdd(&s_hist[w][dreg[k].z >> 7], 1);
            atomicAdd(&s_hist[w][dreg[k].w >> 7], 1);
        }
    }
    __syncthreads();

    for (int b = t; b < NB; b += 256) {
        int tot = s_hist[0][b] + s_hist[1][b] + s_hist[2][b] + s_hist[3][b];
        s_cur[b] = (tot > 0) ? (b * CAP + atomicAdd(&gcnt[b], tot)) : 0;
    }
    __syncthreads();

#pragma unroll
    for (int k = 0; k < 2; ++k) {
        if (val[k]) {
            int bb, pos;
            bb = dreg[k].x >> 7; pos = atomicAdd(&s_cur[bb], 1);
            if (pos < (bb + 1) * CAP) packed[pos] = ((unsigned)sreg[k].x << 7) | (unsigned)(dreg[k].x & 127);
            bb = dreg[k].y >> 7; pos = atomicAdd(&s_cur[bb], 1);
            if (pos < (bb + 1) * CAP) packed[pos] = ((unsigned)sreg[k].y << 7) | (unsigned)(dreg[k].y & 127);
            bb = dreg[k].z >> 7; pos = atomicAdd(&s_cur[bb], 1);
            if (pos < (bb + 1) * CAP) packed[pos] = ((unsigned)sreg[k].z << 7) | (unsigned)(dreg[k].z & 127);
            bb = dreg[k].w >> 7; pos = atomicAdd(&s_cur[bb], 1);
            if (pos < (bb + 1) * CAP) packed[pos] = ((unsigned)sreg[k].w << 7) | (unsigned)(dreg[k].w & 127);
        }
    }
}

// ---------------- pass 2: per-bucket counting sort -> CSR (prefix inline) ----------------
__global__ __launch_bounds__(256) void sort_kernel(
        const unsigned int* __restrict__ packed,
        const int* __restrict__ gcnt,
        int* __restrict__ offsets, int* __restrict__ sorted_src) {
    __shared__ int s_part[256];
    __shared__ unsigned int s_e[CAP];  // 8 KB
    __shared__ int s_hist[NPB];
    __shared__ int s_excl[NPB];
    const int b = blockIdx.x;
    const int t = threadIdx.x;

    // inline exclusive prefix over L2-hot gcnt[0..b-1]
    int psum = 0;
    for (int i = t; i < b; i += 256) psum += gcnt[i];
    s_part[t] = psum;
    __syncthreads();
    for (int off = 128; off > 0; off >>= 1) {
        if (t < off) s_part[t] += s_part[t + off];
        __syncthreads();
    }
    const int base = s_part[0];
    const int nb = min(gcnt[b], CAP);

    for (int i = t; i < NPB; i += 256) s_hist[i] = 0;
    __syncthreads();
    // 4-wide NT reads of the bucket's packed run
    const vint4* p4 = (const vint4*)(packed + (size_t)b * CAP);
    for (int i4 = t; i4 * 4 < nb; i4 += 256) {
        vint4 u4 = __builtin_nontemporal_load(&p4[i4]);
        int i = i4 * 4;
        unsigned int u;
        u = (unsigned)u4.x; if (i + 0 < nb) { s_e[i + 0] = u; atomicAdd(&s_hist[u & 127u], 1); }
        u = (unsigned)u4.y; if (i + 1 < nb) { s_e[i + 1] = u; atomicAdd(&s_hist[u & 127u], 1); }
        u = (unsigned)u4.z; if (i + 2 < nb) { s_e[i + 2] = u; atomicAdd(&s_hist[u & 127u], 1); }
        u = (unsigned)u4.w; if (i + 3 < nb) { s_e[i + 3] = u; atomicAdd(&s_hist[u & 127u], 1); }
    }
    __syncthreads();
    if (t < NPB) s_excl[t] = s_hist[t];
    __syncthreads();
    for (int off = 1; off < NPB; off <<= 1) {
        int v = (t < NPB && t >= off) ? s_excl[t - off] : 0;
        __syncthreads();
        if (t < NPB) s_excl[t] += v;
        __syncthreads();
    }
    if (t < NPB) {
        int excl = s_excl[t] - s_hist[t];
        s_hist[t] = excl;  // becomes cursor
        int node = b * NPB + t;
        if (node < N_NODES) offsets[node] = base + excl;
    }
    __syncthreads();
    for (int i = t; i < nb; i += 256) {
        unsigned int u = s_e[i];
        int lp = atomicAdd(&s_hist[u & 127u], 1);
        sorted_src[base + lp] = (int)(u >> 7);
    }
    if (b == NB - 1 && t == 0) offsets[N_NODES] = N_EDGES;
}

// ---------------- dense (MFMA): [Z|R] = x @ [W_l|W_r] (+bias on R) --------
// 64 nodes/block, 4 waves, output 64x128 fp16. One fused B-tile [64k x 128out].
// A/B frags: contiguous-8 k loads, symmetric formula -> k-permutation cancels.
// C/D: col = lane&15, row = 4*(lane>>4)+j (m89-verified, dtype-independent).
#define AK 72   // padded k stride in halves (144 B, 16B-aligned)
#define OP 136  // s_o row stride in halves (272 B, 16B-aligned)

template <typename XT>
__global__ __launch_bounds__(256) void dense_mfma_kernel(
        const XT* __restrict__ x,
        const float* __restrict__ wl, const float* __restrict__ wr,
        const float* __restrict__ bl,
        __half* __restrict__ z, __half* __restrict__ r, int n_nodes) {
    // union: s_a[64][AK] | s_b[128][AK] during compute; s_o[64][OP] during epilogue
    __shared__ __align__(16) _Float16 smem[64 * AK + 128 * AK];  // 27648 B
    _Float16* s_a = smem;
    _Float16* s_b = smem + 64 * AK;
    _Float16* s_o = smem;  // 64*OP = 8704 halves, fits

    const int t = threadIdx.x;
    const int base = blockIdx.x * 64;

    // stage W_l|W_r transposed to frag order: s_b[outcol][k]
    for (int i = t; i < 4096; i += 256) {
        int k = i >> 6, n = i & 63;
        float vl = wl[i], vr = wr[i];
        s_b[n * AK + k]        = (_Float16)vl;
        s_b[(64 + n) * AK + k] = (_Float16)vr;
    }
    // stage x -> s_a[node][k] fp16
    if constexpr (sizeof(XT) == 4) {
        for (int i = t; i < 1024; i += 256) {
            int n = i >> 4, kq = i & 15;
            float4 v = make_float4(0.f, 0.f, 0.f, 0.f);
            if (base + n < n_nodes) v = ((const float4*)x)[(size_t)(base + n) * 16 + kq];
            _Float16* p = &s_a[n * AK + kq * 4];
            p[0] = (_Float16)v.x; p[1] = (_Float16)v.y;
            p[2] = (_Float16)v.z; p[3] = (_Float16)v.w;
        }
    } else {
        for (int i = t; i < 1024; i += 256) {
            int n = i >> 4, kq = i & 15;
            uint2 v = make_uint2(0u, 0u);
            if (base + n < n_nodes) v = ((const uint2*)x)[(size_t)(base + n) * 16 + kq];  // 16 uint2/row
            *(uint2*)&s_a[n * AK + kq * 4] = v;
        }
    }
    __syncthreads();

    const int lane = t & 63;
    const int w = t >> 6;
    const int mrow = w * 16 + (lane & 15);
    const int kg = (lane >> 4) * 8;
    const int cb = lane & 15;

    f16x8 a0 = *(const f16x8*)&s_a[mrow * AK + kg];       // k in [0,32)
    f16x8 a1 = *(const f16x8*)&s_a[mrow * AK + 32 + kg];  // k in [32,64)
    f32x4 acc[8];
#pragma unroll
    for (int nt = 0; nt < 8; ++nt) {
        int col = nt * 16 + cb;
        f16x8 b0 = *(const f16x8*)&s_b[col * AK + kg];
        f16x8 b1 = *(const f16x8*)&s_b[col * AK + 32 + kg];
        f32x4 c = {0.f, 0.f, 0.f, 0.f};
        c = __builtin_amdgcn_mfma_f32_16x16x32_f16(a0, b0, c, 0, 0, 0);
        c = __builtin_amdgcn_mfma_f32_16x16x32_f16(a1, b1, c, 0, 0, 0);
        acc[nt] = c;
    }
    __syncthreads();  // all LDS frag reads done -> safe to overlay s_o

    // epilogue: acc -> s_o[node][col], bias folded into R columns (col>=64)
#pragma unroll
    for (int nt = 0; nt < 8; ++nt) {
        int col = nt * 16 + cb;
        float bias = (nt >= 4) ? bl[col - 64] : 0.0f;
#pragma unroll
        for (int j = 0; j < 4; ++j) {
            int row = w * 16 + (lane >> 4) * 4 + j;
            s_o[row * OP + col] = (_Float16)(acc[nt][j] + bias);
        }
    }
    __syncthreads();

    // coalesced write-out: thread t -> row t>>2, 32-half (64 B) chunk (t&3)
    {
        int row = t >> 2, q = t & 3;
        size_t gn = (size_t)base + row;
        if (gn < (size_t)n_nodes) {
            const uint4* sp = (const uint4*)&s_o[row * OP + q * 32];
            __half* dp = (q < 2) ? (z + gn * 64 + q * 32) : (r + gn * 64 + (q - 2) * 32);
#pragma unroll
            for (int j = 0; j < 4; ++j)
                ((uint4*)dp)[j] = sp[j];
        }
    }
}

// ---------------- gather: h = PReLU( mean_j z[nbr_j] + r ) ----------------
// R16: 4 nodes/wave, 16 lanes/node, 8 B/lane (uint2 = 4 fp16 channels), with
// R1's CLAMPED UNCONDITIONAL loads (min(j+i,last) addresses, no exec-masked
// loads). R4's divergent per-slot predication shrank VGPR 40->32 -> compiler
// split the load batch -> fewer lines in flight -> 51us regression. Clamped
// loads keep the whole 16-slot batch in one clause (R1-proven); dead-slot
// masking is a cndmask on the loaded value only. 64 lines/wave potential.
template <typename OT>
__global__ __launch_bounds__(256) void gather_kernel(
        const __half* __restrict__ z,
        const __half* __restrict__ r,
        const int* __restrict__ offsets,
        const int* __restrict__ sorted_src,
        const float* __restrict__ a,
        OT* __restrict__ out) {
    const int lane = threadIdx.x & 63;
    const int c4 = lane & 15;                 // channel quad: [4*c4, 4*c4+4)
    const int sub = lane >> 4;                // node sub-index 0..3
    const int node = (blockIdx.x << 4) + ((threadIdx.x >> 6) << 2) + sub;

    const int beg = offsets[node];
    const int deg = offsets[node + 1] - beg;
    const int last = deg - 1;
    const int* sp = sorted_src + beg;
    const uint2* z4 = (const uint2*)z;        // 16 uint2 per 64-half row

    float4 acc = make_float4(0.f, 0.f, 0.f, 0.f);
    for (int j = 0; j < deg; j += 16) {
        int idx[16];
#pragma unroll
        for (int i = 0; i < 16; ++i)
            idx[i] = sp[min(j + i, last)];
        uint2 v[16];
#pragma unroll
        for (int i = 0; i < 16; ++i)
            v[i] = z4[(size_t)idx[i] * 16 + c4];
#pragma unroll
        for (int i = 0; i < 16; ++i) {
            uint2 uv = (j + i < deg) ? v[i] : make_uint2(0u, 0u);
            float2 f0 = __half22float2(*(const __half2*)&uv.x);
            float2 f1 = __half22float2(*(const __half2*)&uv.y);
            acc.x += f0.x; acc.y += f0.y; acc.z += f1.x; acc.w += f1.y;
        }
    }

    const float invd = 1.0f / (float)max(deg, 1);
    uint2 rv2 = ((const uint2*)r)[(size_t)node * 16 + c4];
    float2 r0 = __half22float2(*(const __half2*)&rv2.x);
    float2 r1 = __half22float2(*(const __half2*)&rv2.y);
    float4 av = ((const float4*)a)[c4];

    float h0 = acc.x * invd + r0.x;
    float h1 = acc.y * invd + r0.y;
    float h2 = acc.z * invd + r1.x;
    float h3 = acc.w * invd + r1.y;
    float o0 = h0 >= 0.0f ? h0 : av.x * h0;
    float o1 = h1 >= 0.0f ? h1 : av.y * h1;
    float o2 = h2 >= 0.0f ? h2 : av.z * h2;
    float o3 = h3 >= 0.0f ? h3 : av.w * h3;

    if constexpr (sizeof(OT) == 2) {
        __half2 p0 = __float22half2_rn(make_float2(o0, o1));
        __half2 p1 = __float22half2_rn(make_float2(o2, o3));
        uint2 pk;
        pk.x = *(const unsigned int*)&p0;
        pk.y = *(const unsigned int*)&p1;
        ((uint2*)out)[(size_t)node * 16 + c4] = pk;
    } else {
        ((float4*)out)[(size_t)node * 16 + c4] = make_float4(o0, o1, o2, o3);
    }
}

extern "C" void kernel_launch(void* const* d_in, const int* in_sizes, int n_in,
                              void* d_out, int out_size, void* d_ws, size_t ws_size,
                              hipStream_t stream) {
    const float* x    = (const float*)d_in[0];
    const int*   ei   = (const int*)d_in[1];
    const float* w_l0 = (const float*)d_in[2];
    const float* b_l0 = (const float*)d_in[3];
    const float* w_r0 = (const float*)d_in[4];
    const float* a0   = (const float*)d_in[5];
    const float* w_l1 = (const float*)d_in[6];
    const float* b_l1 = (const float*)d_in[7];
    const float* w_r1 = (const float*)d_in[8];
    const float* a1   = (const float*)d_in[9];
    float* out = (float*)d_out;

    const int* src = ei;            // edge_index[0, :]
    const int* dst = ei + N_EDGES;  // edge_index[1, :]

    // ws: gcnt[1024] | offsets[N+1] | packed[NB*CAP] | sorted_src[E] | Z | R | H (fp16 N*C each)
    int* gcnt            = (int*)d_ws;
    int* offsets         = gcnt + 1024;
    unsigned int* packed = (unsigned int*)(offsets + (N_NODES + 1));
    int* sorted_src      = (int*)(packed + (size_t)NB * CAP);
    __half* Z            = (__half*)(sorted_src + N_EDGES);
    __half* R            = Z + (size_t)N_NODES * C;
    __half* H            = R + (size_t)N_NODES * C;

    hipMemsetAsync(gcnt, 0, 1024 * sizeof(int), stream);

    const int dblocks = (N_NODES + 63) / 64;
    const int nblocks = N_NODES / 16;  // 4 nodes/wave * 4 waves = 16 nodes/block (6250)

    partition_kernel<<<P1_BLOCKS, 256, 0, stream>>>(src, dst, gcnt, packed);
    sort_kernel<<<NB, 256, 0, stream>>>(packed, gcnt, offsets, sorted_src);

    // Layer 0: dense fp32->fp16 (MFMA), gather -> H (fp16)
    dense_mfma_kernel<float><<<dblocks, 256, 0, stream>>>(x, w_l0, w_r0, b_l0, Z, R, N_NODES);
    gather_kernel<__half><<<nblocks, 256, 0, stream>>>(Z, R, offsets, sorted_src, a0, H);

    // Layer 1: dense fp16->fp16 (MFMA), gather -> d_out (fp32)
    dense_mfma_kernel<__half><<<dblocks, 256, 0, stream>>>(H, w_l1, w_r1, b_l1, Z, R, N_NODES);
    gather_kernel<float><<<nblocks, 256, 0, stream>>>(Z, R, offsets, sorted_src, a1, out);
}

// Round 6
// 233.815 us; speedup vs baseline: 1.1025x; 1.0315x over previous
//
#include <hip/hip_runtime.h>
#include <hip/hip_fp16.h>

#define N_NODES 100000
#define N_EDGES 1250000
#define C 64
#define NPB 256          // nodes per bucket (dst >> 8)  [R17: 128->256, cuts scatter fragmentation]
#define NB 391           // ceil(100000/256)
#define CAP 4096         // bucket capacity (mean 3197, sigma ~57 -> +16 sigma headroom)
#define P1_CHUNKQ 1024   // int4-quads per partition block = 4096 edges (306 blocks, ~1.2/CU)
#define P1_BLOCKS 306    // ceil(312500 / 1024)
#define NQ (N_EDGES / 4) // 312500

typedef int vint4 __attribute__((ext_vector_type(4)));
typedef _Float16 f16x8 __attribute__((ext_vector_type(8)));
typedef float f32x4 __attribute__((ext_vector_type(4)));

// ---------------- pass 1: partition edges into 256-node dst-buckets ----------------
// R17: 4096 edges/block over 391 buckets = 10.5 edges/bucket/block -> bucket-run
// scatter writes coalesce ~2.8x better than the 128-node/2048-edge scheme
// (2.6 edges/bucket/block was ~1 isolated line write per bucket per block).
__global__ __launch_bounds__(256) void partition_kernel(
        const int* __restrict__ src, const int* __restrict__ dst,
        int* __restrict__ gcnt, unsigned int* __restrict__ packed) {
    __shared__ int s_hist[4][NB];  // 6.3 KB
    __shared__ int s_cur[NB];      // 1.6 KB
    const int t = threadIdx.x;
    const int w = t >> 6;
    for (int i = t; i < 4 * NB; i += 256) ((int*)s_hist)[i] = 0;
    __syncthreads();

    const int qbase = blockIdx.x * P1_CHUNKQ;
    const vint4* d4 = (const vint4*)dst;
    const vint4* s4 = (const vint4*)src;

    vint4 dreg[4], sreg[4];
    bool val[4];
#pragma unroll
    for (int k = 0; k < 4; ++k) {
        int q = qbase + k * 256 + t;
        val[k] = q < NQ;
        if (val[k]) {
            dreg[k] = __builtin_nontemporal_load(&d4[q]);
            sreg[k] = __builtin_nontemporal_load(&s4[q]);
        }
    }

#pragma unroll
    for (int k = 0; k < 4; ++k) {
        if (val[k]) {
            atomicAdd(&s_hist[w][dreg[k].x >> 8], 1);
            atomicAdd(&s_hist[w][dreg[k].y >> 8], 1);
            atomicAdd(&s_hist[w][dreg[k].z >> 8], 1);
            atomicAdd(&s_hist[w][dreg[k].w >> 8], 1);
        }
    }
    __syncthreads();

    for (int b = t; b < NB; b += 256) {
        int tot = s_hist[0][b] + s_hist[1][b] + s_hist[2][b] + s_hist[3][b];
        s_cur[b] = (tot > 0) ? (b * CAP + atomicAdd(&gcnt[b], tot)) : 0;
    }
    __syncthreads();

#pragma unroll
    for (int k = 0; k < 4; ++k) {
        if (val[k]) {
            int bb, pos;
            bb = dreg[k].x >> 8; pos = atomicAdd(&s_cur[bb], 1);
            if (pos < (bb + 1) * CAP) packed[pos] = ((unsigned)sreg[k].x << 8) | (unsigned)(dreg[k].x & 255);
            bb = dreg[k].y >> 8; pos = atomicAdd(&s_cur[bb], 1);
            if (pos < (bb + 1) * CAP) packed[pos] = ((unsigned)sreg[k].y << 8) | (unsigned)(dreg[k].y & 255);
            bb = dreg[k].z >> 8; pos = atomicAdd(&s_cur[bb], 1);
            if (pos < (bb + 1) * CAP) packed[pos] = ((unsigned)sreg[k].z << 8) | (unsigned)(dreg[k].z & 255);
            bb = dreg[k].w >> 8; pos = atomicAdd(&s_cur[bb], 1);
            if (pos < (bb + 1) * CAP) packed[pos] = ((unsigned)sreg[k].w << 8) | (unsigned)(dreg[k].w & 255);
        }
    }
}

// ---------------- pass 2: per-bucket counting sort -> CSR (prefix inline) ----------------
__global__ __launch_bounds__(256) void sort_kernel(
        const unsigned int* __restrict__ packed,
        const int* __restrict__ gcnt,
        int* __restrict__ offsets, int* __restrict__ sorted_src) {
    __shared__ int s_part[256];
    __shared__ unsigned int s_e[CAP];  // 16 KB
    __shared__ int s_hist[NPB];        // 1 KB
    __shared__ int s_excl[NPB];        // 1 KB
    const int b = blockIdx.x;
    const int t = threadIdx.x;

    // inline exclusive prefix over L2-hot gcnt[0..b-1]
    int psum = 0;
    for (int i = t; i < b; i += 256) psum += gcnt[i];
    s_part[t] = psum;
    __syncthreads();
    for (int off = 128; off > 0; off >>= 1) {
        if (t < off) s_part[t] += s_part[t + off];
        __syncthreads();
    }
    const int base = s_part[0];
    const int nb = min(gcnt[b], CAP);

    s_hist[t] = 0;   // NPB == blockDim
    __syncthreads();
    // 4-wide NT reads of the bucket's packed run
    const vint4* p4 = (const vint4*)(packed + (size_t)b * CAP);
    for (int i4 = t; i4 * 4 < nb; i4 += 256) {
        vint4 u4 = __builtin_nontemporal_load(&p4[i4]);
        int i = i4 * 4;
        unsigned int u;
        u = (unsigned)u4.x; if (i + 0 < nb) { s_e[i + 0] = u; atomicAdd(&s_hist[u & 255u], 1); }
        u = (unsigned)u4.y; if (i + 1 < nb) { s_e[i + 1] = u; atomicAdd(&s_hist[u & 255u], 1); }
        u = (unsigned)u4.z; if (i + 2 < nb) { s_e[i + 2] = u; atomicAdd(&s_hist[u & 255u], 1); }
        u = (unsigned)u4.w; if (i + 3 < nb) { s_e[i + 3] = u; atomicAdd(&s_hist[u & 255u], 1); }
    }
    __syncthreads();
    s_excl[t] = s_hist[t];
    __syncthreads();
    for (int off = 1; off < NPB; off <<= 1) {
        int v = (t >= off) ? s_excl[t - off] : 0;
        __syncthreads();
        s_excl[t] += v;
        __syncthreads();
    }
    {
        int excl = s_excl[t] - s_hist[t];
        s_hist[t] = excl;  // becomes cursor
        int node = b * NPB + t;
        if (node < N_NODES) offsets[node] = base + excl;
    }
    __syncthreads();
    for (int i = t; i < nb; i += 256) {
        unsigned int u = s_e[i];
        int lp = atomicAdd(&s_hist[u & 255u], 1);
        sorted_src[base + lp] = (int)(u >> 8);
    }
    if (b == NB - 1 && t == 0) offsets[N_NODES] = N_EDGES;
}

// ---------------- dense (MFMA): [Z|R] = x @ [W_l|W_r] (+bias on R) --------
// 64 nodes/block, 4 waves, output 64x128 fp16. One fused B-tile [64k x 128out].
// A/B frags: contiguous-8 k loads, symmetric formula -> k-permutation cancels.
// C/D: col = lane&15, row = 4*(lane>>4)+j (m89-verified, dtype-independent).
#define AK 72   // padded k stride in halves (144 B, 16B-aligned)
#define OP 136  // s_o row stride in halves (272 B, 16B-aligned)

template <typename XT>
__global__ __launch_bounds__(256) void dense_mfma_kernel(
        const XT* __restrict__ x,
        const float* __restrict__ wl, const float* __restrict__ wr,
        const float* __restrict__ bl,
        __half* __restrict__ z, __half* __restrict__ r, int n_nodes) {
    // union: s_a[64][AK] | s_b[128][AK] during compute; s_o[64][OP] during epilogue
    __shared__ __align__(16) _Float16 smem[64 * AK + 128 * AK];  // 27648 B
    _Float16* s_a = smem;
    _Float16* s_b = smem + 64 * AK;
    _Float16* s_o = smem;  // 64*OP = 8704 halves, fits

    const int t = threadIdx.x;
    const int base = blockIdx.x * 64;

    // stage W_l|W_r transposed to frag order: s_b[outcol][k]
    for (int i = t; i < 4096; i += 256) {
        int k = i >> 6, n = i & 63;
        float vl = wl[i], vr = wr[i];
        s_b[n * AK + k]        = (_Float16)vl;
        s_b[(64 + n) * AK + k] = (_Float16)vr;
    }
    // stage x -> s_a[node][k] fp16
    if constexpr (sizeof(XT) == 4) {
        for (int i = t; i < 1024; i += 256) {
            int n = i >> 4, kq = i & 15;
            float4 v = make_float4(0.f, 0.f, 0.f, 0.f);
            if (base + n < n_nodes) v = ((const float4*)x)[(size_t)(base + n) * 16 + kq];
            _Float16* p = &s_a[n * AK + kq * 4];
            p[0] = (_Float16)v.x; p[1] = (_Float16)v.y;
            p[2] = (_Float16)v.z; p[3] = (_Float16)v.w;
        }
    } else {
        for (int i = t; i < 1024; i += 256) {
            int n = i >> 4, kq = i & 15;
            uint2 v = make_uint2(0u, 0u);
            if (base + n < n_nodes) v = ((const uint2*)x)[(size_t)(base + n) * 16 + kq];  // 16 uint2/row
            *(uint2*)&s_a[n * AK + kq * 4] = v;
        }
    }
    __syncthreads();

    const int lane = t & 63;
    const int w = t >> 6;
    const int mrow = w * 16 + (lane & 15);
    const int kg = (lane >> 4) * 8;
    const int cb = lane & 15;

    f16x8 a0 = *(const f16x8*)&s_a[mrow * AK + kg];       // k in [0,32)
    f16x8 a1 = *(const f16x8*)&s_a[mrow * AK + 32 + kg];  // k in [32,64)
    f32x4 acc[8];
#pragma unroll
    for (int nt = 0; nt < 8; ++nt) {
        int col = nt * 16 + cb;
        f16x8 b0 = *(const f16x8*)&s_b[col * AK + kg];
        f16x8 b1 = *(const f16x8*)&s_b[col * AK + 32 + kg];
        f32x4 c = {0.f, 0.f, 0.f, 0.f};
        c = __builtin_amdgcn_mfma_f32_16x16x32_f16(a0, b0, c, 0, 0, 0);
        c = __builtin_amdgcn_mfma_f32_16x16x32_f16(a1, b1, c, 0, 0, 0);
        acc[nt] = c;
    }
    __syncthreads();  // all LDS frag reads done -> safe to overlay s_o

    // epilogue: acc -> s_o[node][col], bias folded into R columns (col>=64)
#pragma unroll
    for (int nt = 0; nt < 8; ++nt) {
        int col = nt * 16 + cb;
        float bias = (nt >= 4) ? bl[col - 64] : 0.0f;
#pragma unroll
        for (int j = 0; j < 4; ++j) {
            int row = w * 16 + (lane >> 4) * 4 + j;
            s_o[row * OP + col] = (_Float16)(acc[nt][j] + bias);
        }
    }
    __syncthreads();

    // coalesced write-out: thread t -> row t>>2, 32-half (64 B) chunk (t&3)
    {
        int row = t >> 2, q = t & 3;
        size_t gn = (size_t)base + row;
        if (gn < (size_t)n_nodes) {
            const uint4* sp = (const uint4*)&s_o[row * OP + q * 32];
            __half* dp = (q < 2) ? (z + gn * 64 + q * 32) : (r + gn * 64 + (q - 2) * 32);
#pragma unroll
            for (int j = 0; j < 4; ++j)
                ((uint4*)dp)[j] = sp[j];
        }
    }
}

// ---------------- gather: h = PReLU( mean_j z[nbr_j] + r ) ----------------
// R16: 4 nodes/wave, 16 lanes/node, 8 B/lane, clamped unconditional loads.
// At the random-line system ceiling (~3.2-3.5 TB/s) -- unchanged in R17.
template <typename OT>
__global__ __launch_bounds__(256) void gather_kernel(
        const __half* __restrict__ z,
        const __half* __restrict__ r,
        const int* __restrict__ offsets,
        const int* __restrict__ sorted_src,
        const float* __restrict__ a,
        OT* __restrict__ out) {
    const int lane = threadIdx.x & 63;
    const int c4 = lane & 15;                 // channel quad: [4*c4, 4*c4+4)
    const int sub = lane >> 4;                // node sub-index 0..3
    const int node = (blockIdx.x << 4) + ((threadIdx.x >> 6) << 2) + sub;

    const int beg = offsets[node];
    const int deg = offsets[node + 1] - beg;
    const int last = deg - 1;
    const int* sp = sorted_src + beg;
    const uint2* z4 = (const uint2*)z;        // 16 uint2 per 64-half row

    float4 acc = make_float4(0.f, 0.f, 0.f, 0.f);
    for (int j = 0; j < deg; j += 16) {
        int idx[16];
#pragma unroll
        for (int i = 0; i < 16; ++i)
            idx[i] = sp[min(j + i, last)];
        uint2 v[16];
#pragma unroll
        for (int i = 0; i < 16; ++i)
            v[i] = z4[(size_t)idx[i] * 16 + c4];
#pragma unroll
        for (int i = 0; i < 16; ++i) {
            uint2 uv = (j + i < deg) ? v[i] : make_uint2(0u, 0u);
            float2 f0 = __half22float2(*(const __half2*)&uv.x);
            float2 f1 = __half22float2(*(const __half2*)&uv.y);
            acc.x += f0.x; acc.y += f0.y; acc.z += f1.x; acc.w += f1.y;
        }
    }

    const float invd = 1.0f / (float)max(deg, 1);
    uint2 rv2 = ((const uint2*)r)[(size_t)node * 16 + c4];
    float2 r0 = __half22float2(*(const __half2*)&rv2.x);
    float2 r1 = __half22float2(*(const __half2*)&rv2.y);
    float4 av = ((const float4*)a)[c4];

    float h0 = acc.x * invd + r0.x;
    float h1 = acc.y * invd + r0.y;
    float h2 = acc.z * invd + r1.x;
    float h3 = acc.w * invd + r1.y;
    float o0 = h0 >= 0.0f ? h0 : av.x * h0;
    float o1 = h1 >= 0.0f ? h1 : av.y * h1;
    float o2 = h2 >= 0.0f ? h2 : av.z * h2;
    float o3 = h3 >= 0.0f ? h3 : av.w * h3;

    if constexpr (sizeof(OT) == 2) {
        __half2 p0 = __float22half2_rn(make_float2(o0, o1));
        __half2 p1 = __float22half2_rn(make_float2(o2, o3));
        uint2 pk;
        pk.x = *(const unsigned int*)&p0;
        pk.y = *(const unsigned int*)&p1;
        ((uint2*)out)[(size_t)node * 16 + c4] = pk;
    } else {
        ((float4*)out)[(size_t)node * 16 + c4] = make_float4(o0, o1, o2, o3);
    }
}

extern "C" void kernel_launch(void* const* d_in, const int* in_sizes, int n_in,
                              void* d_out, int out_size, void* d_ws, size_t ws_size,
                              hipStream_t stream) {
    const float* x    = (const float*)d_in[0];
    const int*   ei   = (const int*)d_in[1];
    const float* w_l0 = (const float*)d_in[2];
    const float* b_l0 = (const float*)d_in[3];
    const float* w_r0 = (const float*)d_in[4];
    const float* a0   = (const float*)d_in[5];
    const float* w_l1 = (const float*)d_in[6];
    const float* b_l1 = (const float*)d_in[7];
    const float* w_r1 = (const float*)d_in[8];
    const float* a1   = (const float*)d_in[9];
    float* out = (float*)d_out;

    const int* src = ei;            // edge_index[0, :]
    const int* dst = ei + N_EDGES;  // edge_index[1, :]

    // ws: gcnt[1024] | offsets[N+1] | packed[NB*CAP] | sorted_src[E] | Z | R | H (fp16 N*C each)
    int* gcnt            = (int*)d_ws;
    int* offsets         = gcnt + 1024;
    unsigned int* packed = (unsigned int*)(offsets + (N_NODES + 1));
    int* sorted_src      = (int*)(packed + (size_t)NB * CAP);
    __half* Z            = (__half*)(sorted_src + N_EDGES);
    __half* R            = Z + (size_t)N_NODES * C;
    __half* H            = R + (size_t)N_NODES * C;

    hipMemsetAsync(gcnt, 0, 1024 * sizeof(int), stream);

    const int dblocks = (N_NODES + 63) / 64;
    const int nblocks = N_NODES / 16;  // 4 nodes/wave * 4 waves = 16 nodes/block (6250)

    partition_kernel<<<P1_BLOCKS, 256, 0, stream>>>(src, dst, gcnt, packed);
    sort_kernel<<<NB, 256, 0, stream>>>(packed, gcnt, offsets, sorted_src);

    // Layer 0: dense fp32->fp16 (MFMA), gather -> H (fp16)
    dense_mfma_kernel<float><<<dblocks, 256, 0, stream>>>(x, w_l0, w_r0, b_l0, Z, R, N_NODES);
    gather_kernel<__half><<<nblocks, 256, 0, stream>>>(Z, R, offsets, sorted_src, a0, H);

    // Layer 1: dense fp16->fp16 (MFMA), gather -> d_out (fp32)
    dense_mfma_kernel<__half><<<dblocks, 256, 0, stream>>>(H, w_l1, w_r1, b_l1, Z, R, N_NODES);
    gather_kernel<float><<<nblocks, 256, 0, stream>>>(Z, R, offsets, sorted_src, a1, out);
}